// Round 11
// baseline (69.574 us; speedup 1.0000x reference)
//
#include <hip/hip_runtime.h>
#include <stdint.h>

typedef unsigned short u16;
typedef unsigned int u32;
typedef __bf16 bf16x8 __attribute__((ext_vector_type(8)));
typedef float f32x16 __attribute__((ext_vector_type(16)));

#define MFMA32 __builtin_amdgcn_mfma_f32_32x32x16_bf16

// ---------------- helpers ----------------

__device__ __forceinline__ u16 f2bf(float f) {
    u32 u = __builtin_bit_cast(u32, f);
    u32 r = (u + 0x7FFFu + ((u >> 16) & 1u)) >> 16;
    return (u16)r;
}

__device__ __forceinline__ void gload_lds16(const u16* g, u16* l) {
    __builtin_amdgcn_global_load_lds(
        (const __attribute__((address_space(1))) void*)g,
        (__attribute__((address_space(3))) void*)l,
        16, 0, 0);
}

// ================= kernel 1: merged conv_x + prep_w =================
// blocks [0, convBlocks): x fp32 -> bf16 (8 elems/thread).
// blocks [convBlocks, convBlocks+512): fused TT weight precompute ->
//   Wt[o*4+s][i] (bf16 [4096][1024]) = sum_{q,r} c0[b,w,q,s]*c1[q,c,x,r,s]*c2[r,d,y,s]
//   i=(b*128+c*8+d), o=(w*128+x*8+y); 512 blocks = (bc=128)x(part=4).

__global__ __launch_bounds__(256) void pre_kernel(const float* __restrict__ x,
                                                  const float* __restrict__ c0,
                                                  const float* __restrict__ c1,
                                                  const float* __restrict__ c2,
                                                  u16* __restrict__ xb,
                                                  u16* __restrict__ Wt,
                                                  int convBlocks, int nElem) {
    __shared__ float smem[10496];   // 41 KB: c0(256) c1(4096) c2(2048) w1(4096)
    const int t = threadIdx.x;

    if ((int)blockIdx.x < convBlocks) {
        int i = (blockIdx.x * 256 + t) * 8;
        if (i + 8 > nElem) return;
        float4 a = *reinterpret_cast<const float4*>(x + i);
        float4 b = *reinterpret_cast<const float4*>(x + i + 4);
        uint4 pk;
        pk.x = (u32)f2bf(a.x) | ((u32)f2bf(a.y) << 16);
        pk.y = (u32)f2bf(a.z) | ((u32)f2bf(a.w) << 16);
        pk.z = (u32)f2bf(b.x) | ((u32)f2bf(b.y) << 16);
        pk.w = (u32)f2bf(b.z) | ((u32)f2bf(b.w) << 16);
        *reinterpret_cast<uint4*>(xb + i) = pk;
        return;
    }

    float* l_c0 = smem;           // [w][q][s]     (slice at fixed b)
    float* l_c1 = smem + 256;     // [q][x][r][s]  (slice at fixed c)
    float* l_c2 = smem + 4352;    // [r][d][y][s]  (full)
    float* l_w1 = smem + 6400;    // [w][x][r][s]

    const int bid = blockIdx.x - convBlocks;
    const int bc = bid >> 2;      // 0..127
    const int part = bid & 3;     // 0..3 : w-pair {2p, 2p+1}
    const int b = bc >> 4, c = bc & 15;

    l_c0[t] = c0[b * 256 + t];
#pragma unroll
    for (int q = 0; q < 8; ++q) {
        l_c1[q * 512 + t]       = c1[(q * 16 + c) * 512 + t];
        l_c1[q * 512 + t + 256] = c1[(q * 16 + c) * 512 + t + 256];
    }
#pragma unroll
    for (int j = 0; j < 8; ++j) l_c2[t + 256 * j] = c2[t + 256 * j];
    __syncthreads();

    // W1[w][x][r][s] = sum_q c0[w,q,s] * c1[q,x,r,s]   (only w in {2p,2p+1})
#pragma unroll
    for (int j = 0; j < 4; ++j) {
        int idx = t + 256 * (part * 4 + j);   // ((w*16+x)*8+r)*4+s
        int s = idx & 3;
        int r = (idx >> 2) & 7;
        int xx = (idx >> 5) & 15;
        int w = idx >> 9;
        float acc = 0.f;
#pragma unroll
        for (int q = 0; q < 8; ++q)
            acc += l_c0[(w * 8 + q) * 4 + s] * l_c1[q * 512 + (xx * 8 + r) * 4 + s];
        l_w1[idx] = acc;
    }
    __syncthreads();

    // Wt[(o*4+s)][b*128+c*8+d] = sum_r W1[w,x,r,s] * c2[r,d,y,s]
#pragma unroll
    for (int j = 0; j < 4; ++j) {
        int idx = t + 256 * (part * 4 + j);   // ((w*16+x)*8+y)*4+s == o*4+s
        int s = idx & 3;
        int y = (idx >> 2) & 7;
        int xx = (idx >> 5) & 15;
        int w = idx >> 9;
        float acc[8] = {0.f, 0.f, 0.f, 0.f, 0.f, 0.f, 0.f, 0.f};
#pragma unroll
        for (int r = 0; r < 8; ++r) {
            float w1 = l_w1[((w * 16 + xx) * 8 + r) * 4 + s];
#pragma unroll
            for (int d = 0; d < 8; ++d)
                acc[d] += w1 * l_c2[((r * 8 + d) * 8 + y) * 4 + s];
        }
        uint4 pk;
        pk.x = (u32)f2bf(acc[0]) | ((u32)f2bf(acc[1]) << 16);
        pk.y = (u32)f2bf(acc[2]) | ((u32)f2bf(acc[3]) << 16);
        pk.z = (u32)f2bf(acc[4]) | ((u32)f2bf(acc[5]) << 16);
        pk.w = (u32)f2bf(acc[6]) | ((u32)f2bf(acc[7]) << 16);
        *reinterpret_cast<uint4*>(&Wt[(size_t)idx * 1024 + b * 128 + c * 8]) = pk;
    }
}

// ========== kernel 2: 256x256 GEMM, 32x32x16 MFMA, reg-dbuf frags ==========
// C[M][N] = A[M][K] * B[N][K]^T.  A = xb, B = Wt (both bf16 [4096][1024]).
// 512 threads = 8 waves (2M x 4N); per-wave 128x64 = 4x2 frags of 32x32
// (acc = 8 x f32x16 = 128 VGPR). K-step BK=32 (2 MFMA-k of 16), NT=32 steps.
//
// PIPELINE (this round's change): register-level fragment double-buffer.
// Step kt: [DMA tile kt+3 -> slot (kt+3)&3] ; [ds_read tile kt+1's 12 frags
// into the ALTERNATE named set] ; [16 MFMA on current set -- waits only on
// LAST step's reads (compiler lgkmcnt(12))] ; vmcnt(4) ; barrier.
// MFMAs never wait on this step's ds_reads -> DS and MFMA overlap within
// the wave. 4 LDS slots x 32 KB = 128 KiB; DMA flight ~2.5 steps.
// vmcnt(4) at step end: outstanding = tiles kt+2 (needed next step) + kt+3
// (just issued) = 8 loads; allow 4 newest -> kt+2 resident before its reads.
//
// LDS swizzle (row = 32 u16 = 64 B): phys 16B-chunk = logical ^ ((row>>1)&3)
// -> 8 (row&1, chunk) combos per 16 rows, conflict-free (R4/R10: measured 0).
// Both-sides involution: linear gload_lds dest + pre-swizzled global source
// + same XOR on ds_read.
// 32x32x16 operand map (extension of verified 16x16x32): A/B lane ln reads
// row (ln&31), k = (ln>>5)*8 + j. C/D (m74/m101-verified): col = ln&31,
// row = (reg&3) + 8*(reg>>2) + 4*(ln>>5).
// XCD swizzle (T1, bijective, grid 256 = 16x16).

#define SLOT_U16 8192   // one slot of A (or B): 256 rows * 32 u16 = 16 KB

__global__ __launch_bounds__(512, 2) void gemm256_kernel(const u16* __restrict__ A,
                                                         const u16* __restrict__ B,
                                                         float* __restrict__ C,
                                                         int M, int N, int K) {
    __shared__ u16 As[4 * SLOT_U16];  // 64 KB
    __shared__ u16 Bs[4 * SLOT_U16];  // 64 KB

    const int t   = threadIdx.x;
    const int ln  = t & 63;
    const int wid = t >> 6;          // 0..7
    const int wr  = wid >> 2;        // 0..1 -> M offset wr*128
    const int wc  = wid & 3;         // 0..3 -> N offset wc*64

    // ---- XCD-aware bijective block swizzle (grid 256 = 16 x 16) ----
    const int bid = blockIdx.x;
    const int xcd = bid & 7;
    const int r8  = bid >> 3;            // 0..31
    const int bx  = (xcd & 1) * 8 + (r8 & 7);
    const int by  = (xcd >> 1) * 4 + (r8 >> 3);
    const int m0  = by * 256;
    const int n0  = bx * 256;
    const int NT  = K >> 5;          // 32 K-steps

    // ---- fragment addressing (32x32x16): row = base + (ln&31) ----
    const int l31 = ln & 31;
    const int h   = ln >> 5;                      // k-half-of-16 selector
    const int sx  = (l31 >> 1) & 3;               // swizzle term (base%32==0)
    const int ch0 = ((sx >> 1) << 1) | (h ^ (sx & 1));  // phys chunk, ks=0
    const int aoff0 = (wr * 128 + l31) * 32 + ch0 * 8;  // + fm*1024 ; ks1: ^16
    const int boff0 = (wc * 64  + l31) * 32 + ch0 * 8;  // + g*1024  ; ks1: ^16

    // ---- staging: tile = 1024 chunks of 16B; thread t does chunks t, t+512.
    const int ca = t, cb = t + 512;
    const int ra_ = ca >> 2, sa_ = ((ca & 3) ^ ((ra_ >> 1) & 3)) * 8;
    const int rb_ = cb >> 2, sb_ = ((cb & 3) ^ ((rb_ >> 1) & 3)) * 8;
    const u16* Asrc0 = A + (size_t)(m0 + ra_) * K + sa_;
    const u16* Asrc1 = A + (size_t)(m0 + rb_) * K + sb_;
    const u16* Bsrc0 = B + (size_t)(n0 + ra_) * K + sa_;
    const u16* Bsrc1 = B + (size_t)(n0 + rb_) * K + sb_;

    f32x16 acc00 = {}, acc01 = {}, acc10 = {}, acc11 = {};
    f32x16 acc20 = {}, acc21 = {}, acc30 = {}, acc31 = {};

    bf16x8 Pa0k0, Pa0k1, Pa1k0, Pa1k1, Pa2k0, Pa2k1, Pa3k0, Pa3k1;
    bf16x8 Pb0k0, Pb0k1, Pb1k0, Pb1k1;
    bf16x8 Qa0k0, Qa0k1, Qa1k0, Qa1k1, Qa2k0, Qa2k1, Qa3k0, Qa3k1;
    bf16x8 Qb0k0, Qb0k1, Qb1k0, Qb1k1;

#define STAGE(T)                                                       \
    {   const int kc_ = (T) * 32;                                      \
        u16* Ad_ = As + ((T) & 3) * SLOT_U16;                          \
        u16* Bd_ = Bs + ((T) & 3) * SLOT_U16;                          \
        gload_lds16(Asrc0 + kc_, Ad_ + ca * 8);                        \
        gload_lds16(Asrc1 + kc_, Ad_ + cb * 8);                        \
        gload_lds16(Bsrc0 + kc_, Bd_ + ca * 8);                        \
        gload_lds16(Bsrc1 + kc_, Bd_ + cb * 8);   }

#define READ_FRAGS(S, SL)                                              \
    {   const u16* Ab_ = As + (SL) * SLOT_U16;                         \
        const u16* Bb_ = Bs + (SL) * SLOT_U16;                         \
        S##a0k0 = *(const bf16x8*)(Ab_ + aoff0);                       \
        S##a0k1 = *(const bf16x8*)(Ab_ + (aoff0 ^ 16));                \
        S##a1k0 = *(const bf16x8*)(Ab_ + aoff0 + 1024);                \
        S##a1k1 = *(const bf16x8*)(Ab_ + (aoff0 ^ 16) + 1024);         \
        S##a2k0 = *(const bf16x8*)(Ab_ + aoff0 + 2048);                \
        S##a2k1 = *(const bf16x8*)(Ab_ + (aoff0 ^ 16) + 2048);         \
        S##a3k0 = *(const bf16x8*)(Ab_ + aoff0 + 3072);                \
        S##a3k1 = *(const bf16x8*)(Ab_ + (aoff0 ^ 16) + 3072);         \
        S##b0k0 = *(const bf16x8*)(Bb_ + boff0);                       \
        S##b0k1 = *(const bf16x8*)(Bb_ + (boff0 ^ 16));                \
        S##b1k0 = *(const bf16x8*)(Bb_ + boff0 + 1024);                \
        S##b1k1 = *(const bf16x8*)(Bb_ + (boff0 ^ 16) + 1024);   }

#define MFMA_ALL(S)                                                    \
    acc00 = MFMA32(S##a0k0, S##b0k0, acc00, 0, 0, 0);                  \
    acc01 = MFMA32(S##a0k0, S##b1k0, acc01, 0, 0, 0);                  \
    acc10 = MFMA32(S##a1k0, S##b0k0, acc10, 0, 0, 0);                  \
    acc11 = MFMA32(S##a1k0, S##b1k0, acc11, 0, 0, 0);                  \
    acc20 = MFMA32(S##a2k0, S##b0k0, acc20, 0, 0, 0);                  \
    acc21 = MFMA32(S##a2k0, S##b1k0, acc21, 0, 0, 0);                  \
    acc30 = MFMA32(S##a3k0, S##b0k0, acc30, 0, 0, 0);                  \
    acc31 = MFMA32(S##a3k0, S##b1k0, acc31, 0, 0, 0);                  \
    acc00 = MFMA32(S##a0k1, S##b0k1, acc00, 0, 0, 0);                  \
    acc01 = MFMA32(S##a0k1, S##b1k1, acc01, 0, 0, 0);                  \
    acc10 = MFMA32(S##a1k1, S##b0k1, acc10, 0, 0, 0);                  \
    acc11 = MFMA32(S##a1k1, S##b1k1, acc11, 0, 0, 0);                  \
    acc20 = MFMA32(S##a2k1, S##b0k1, acc20, 0, 0, 0);                  \
    acc21 = MFMA32(S##a2k1, S##b1k1, acc21, 0, 0, 0);                  \
    acc30 = MFMA32(S##a3k1, S##b0k1, acc30, 0, 0, 0);                  \
    acc31 = MFMA32(S##a3k1, S##b1k1, acc31, 0, 0, 0);

#define STEP(KT, CUR, NXT)                                             \
    {   if ((KT) + 3 < NT) STAGE((KT) + 3);                            \
        if ((KT) + 1 < NT) READ_FRAGS(NXT, ((KT) + 1) & 3);            \
        MFMA_ALL(CUR);                                                 \
        if ((KT) + 3 < NT) {                                           \
            asm volatile("s_waitcnt vmcnt(4)" ::: "memory");           \
        } else {                                                       \
            asm volatile("s_waitcnt vmcnt(0)" ::: "memory");           \
        }                                                              \
        __builtin_amdgcn_s_barrier();   }

    // ---- prologue: stage tiles 0,1,2; tiles 0 AND 1 resident; read tile 0 ----
    STAGE(0);
    STAGE(1);
    STAGE(2);
    asm volatile("s_waitcnt vmcnt(4)" ::: "memory");   // tiles 0,1 done
    __builtin_amdgcn_s_barrier();
    READ_FRAGS(P, 0);

    for (int kt = 0; kt < NT; kt += 2) {
        STEP(kt, P, Q);
        STEP(kt + 1, Q, P);
    }
#undef STEP
#undef MFMA_ALL
#undef READ_FRAGS
#undef STAGE

    // ---- epilogue: C/D col=ln&31, row=(r&3)+8*(r>>2)+4*(ln>>5) ----
    const int crb  = m0 + wr * 128 + 4 * h;
    const int ccol = n0 + wc * 64 + l31;
#define STORE(ACC, FM, G)                                              \
    _Pragma("unroll")                                                  \
    for (int r = 0; r < 16; ++r) {                                     \
        int row = crb + (FM) * 32 + (r & 3) + 8 * (r >> 2);            \
        C[(size_t)row * N + ccol + (G) * 32] = ACC[r];                 \
    }
    STORE(acc00, 0, 0); STORE(acc01, 0, 1);
    STORE(acc10, 1, 0); STORE(acc11, 1, 1);
    STORE(acc20, 2, 0); STORE(acc21, 2, 1);
    STORE(acc30, 3, 0); STORE(acc31, 3, 1);
#undef STORE
}

// ---------------- launch ----------------

extern "C" void kernel_launch(void* const* d_in, const int* in_sizes, int n_in,
                              void* d_out, int out_size, void* d_ws, size_t ws_size,
                              hipStream_t stream) {
    const float* x  = (const float*)d_in[0];
    const float* c0 = (const float*)d_in[1];
    const float* c1 = (const float*)d_in[2];
    const float* c2 = (const float*)d_in[3];
    float* out = (float*)d_out;

    const int K = 1024;             // input dim
    const int N = 4096;             // OUT_DIM * SUP
    const int M = in_sizes[0] / K;  // tokens = B*S

    u16* xb = (u16*)d_ws;                        // M*K bf16
    u16* Wt = (u16*)d_ws + (size_t)M * K;        // N*K bf16

    const int convBlocks = (M * K) / (256 * 8);
    pre_kernel<<<convBlocks + 512, 256, 0, stream>>>(x, c0, c1, c2, xb, Wt,
                                                     convBlocks, M * K);

    gemm256_kernel<<<(N / 256) * (M / 256), 512, 0, stream>>>(xb, Wt, out, M, N, K);
}

// Round 12
// 58.042 us; speedup vs baseline: 1.1987x; 1.1987x over previous
//
#include <hip/hip_runtime.h>
#include <stdint.h>

typedef unsigned short u16;
typedef unsigned int u32;
typedef __bf16 bf16x8 __attribute__((ext_vector_type(8)));
typedef float f32x4 __attribute__((ext_vector_type(4)));

#define MFMA16 __builtin_amdgcn_mfma_f32_16x16x32_bf16

// ---------------- helpers ----------------

__device__ __forceinline__ u16 f2bf(float f) {
    u32 u = __builtin_bit_cast(u32, f);
    u32 r = (u + 0x7FFFu + ((u >> 16) & 1u)) >> 16;
    return (u16)r;
}

__device__ __forceinline__ void gload_lds16(const u16* g, u16* l) {
    __builtin_amdgcn_global_load_lds(
        (const __attribute__((address_space(1))) void*)g,
        (__attribute__((address_space(3))) void*)l,
        16, 0, 0);
}

// ================= kernel 1: merged conv_x + prep_w =================
// blocks [0, convBlocks): x fp32 -> bf16 (8 elems/thread).
// blocks [convBlocks, convBlocks+512): fused TT weight precompute ->
//   Wt[o*4+s][i] (bf16 [4096][1024]) = sum_{q,r} c0[b,w,q,s]*c1[q,c,x,r,s]*c2[r,d,y,s]
//   i=(b*128+c*8+d), o=(w*128+x*8+y); 512 blocks = (bc=128)x(part=4).

__global__ __launch_bounds__(256) void pre_kernel(const float* __restrict__ x,
                                                  const float* __restrict__ c0,
                                                  const float* __restrict__ c1,
                                                  const float* __restrict__ c2,
                                                  u16* __restrict__ xb,
                                                  u16* __restrict__ Wt,
                                                  int convBlocks, int nElem) {
    __shared__ float smem[10496];   // 41 KB: c0(256) c1(4096) c2(2048) w1(4096)
    const int t = threadIdx.x;

    if ((int)blockIdx.x < convBlocks) {
        int i = (blockIdx.x * 256 + t) * 8;
        if (i + 8 > nElem) return;
        float4 a = *reinterpret_cast<const float4*>(x + i);
        float4 b = *reinterpret_cast<const float4*>(x + i + 4);
        uint4 pk;
        pk.x = (u32)f2bf(a.x) | ((u32)f2bf(a.y) << 16);
        pk.y = (u32)f2bf(a.z) | ((u32)f2bf(a.w) << 16);
        pk.z = (u32)f2bf(b.x) | ((u32)f2bf(b.y) << 16);
        pk.w = (u32)f2bf(b.z) | ((u32)f2bf(b.w) << 16);
        *reinterpret_cast<uint4*>(xb + i) = pk;
        return;
    }

    float* l_c0 = smem;           // [w][q][s]     (slice at fixed b)
    float* l_c1 = smem + 256;     // [q][x][r][s]  (slice at fixed c)
    float* l_c2 = smem + 4352;    // [r][d][y][s]  (full)
    float* l_w1 = smem + 6400;    // [w][x][r][s]

    const int bid = blockIdx.x - convBlocks;
    const int bc = bid >> 2;      // 0..127
    const int part = bid & 3;     // 0..3 : w-pair {2p, 2p+1}
    const int b = bc >> 4, c = bc & 15;

    l_c0[t] = c0[b * 256 + t];
#pragma unroll
    for (int q = 0; q < 8; ++q) {
        l_c1[q * 512 + t]       = c1[(q * 16 + c) * 512 + t];
        l_c1[q * 512 + t + 256] = c1[(q * 16 + c) * 512 + t + 256];
    }
#pragma unroll
    for (int j = 0; j < 8; ++j) l_c2[t + 256 * j] = c2[t + 256 * j];
    __syncthreads();

    // W1[w][x][r][s] = sum_q c0[w,q,s] * c1[q,x,r,s]   (only w in {2p,2p+1})
#pragma unroll
    for (int j = 0; j < 4; ++j) {
        int idx = t + 256 * (part * 4 + j);   // ((w*16+x)*8+r)*4+s
        int s = idx & 3;
        int r = (idx >> 2) & 7;
        int xx = (idx >> 5) & 15;
        int w = idx >> 9;
        float acc = 0.f;
#pragma unroll
        for (int q = 0; q < 8; ++q)
            acc += l_c0[(w * 8 + q) * 4 + s] * l_c1[q * 512 + (xx * 8 + r) * 4 + s];
        l_w1[idx] = acc;
    }
    __syncthreads();

    // Wt[(o*4+s)][b*128+c*8+d] = sum_r W1[w,x,r,s] * c2[r,d,y,s]
#pragma unroll
    for (int j = 0; j < 4; ++j) {
        int idx = t + 256 * (part * 4 + j);   // ((w*16+x)*8+y)*4+s == o*4+s
        int s = idx & 3;
        int y = (idx >> 2) & 7;
        int xx = (idx >> 5) & 15;
        int w = idx >> 9;
        float acc[8] = {0.f, 0.f, 0.f, 0.f, 0.f, 0.f, 0.f, 0.f};
#pragma unroll
        for (int r = 0; r < 8; ++r) {
            float w1 = l_w1[((w * 16 + xx) * 8 + r) * 4 + s];
#pragma unroll
            for (int d = 0; d < 8; ++d)
                acc[d] += w1 * l_c2[((r * 8 + d) * 8 + y) * 4 + s];
        }
        uint4 pk;
        pk.x = (u32)f2bf(acc[0]) | ((u32)f2bf(acc[1]) << 16);
        pk.y = (u32)f2bf(acc[2]) | ((u32)f2bf(acc[3]) << 16);
        pk.z = (u32)f2bf(acc[4]) | ((u32)f2bf(acc[5]) << 16);
        pk.w = (u32)f2bf(acc[6]) | ((u32)f2bf(acc[7]) << 16);
        *reinterpret_cast<uint4*>(&Wt[(size_t)idx * 1024 + b * 128 + c * 8]) = pk;
    }
}

// ========== kernel 2: 256x256 8-phase GEMM, COUNTED vmcnt (T3+T4) ==========
// C[M][N] = A[M][K] * B[N][K]^T.  A = xb, B = Wt (both bf16 [4096][1024]).
// 512 threads = 8 waves (2M x 4N); per-wave 128x64 = acc[8][4] 16x16 frags.
// K-tile BK=64 (rows are 128 B); 2 dbuf slots; LDS 128 KiB.
//
// Per K-tile, 4 phases: {ds_read A fm-pair (+all B in ph0) ; stage 2 DMA
// loads of tile t+1 ; barrier ; setprio(1) ; 16 MFMA ; setprio(0) ;
// [counted vmcnt] ; barrier}.  B held in regs across the tile (24
// ds_read/tile/wave -> LDS 2.26k cy < MFMA 2.48k cy: MFMA-bound).
//
// STAGING ORDER for tile t+1 (2 loads/phase; each load = 64 rows x 64 cols):
//   ph0: B-h0 L0,L1 | ph1: B-h1 L0,L1 | ph2: A-h0 L0, A-h1 L0 | ph3: A-h0 L1, A-h1 L1
// COUNTED WAITS (per-wave; never 0 in steady state):
//   end-ph1: vmcnt(4) -> own tile's A L1 loads (rows 64-127/192-255) resident
//            before ph2 reads fm4,5 (rows 64-95).  [last tile: vmcnt(0)]
//   end-ph3: vmcnt(2) -> t+1's B + A-L0 resident (ph0/ph1 reads covered);
//            t+1's A-L1 pair stays in flight across the boundary barrier.
//
// LDS swizzle (rows = 64 u16 = 128 B = 8 chunks of 16 B): phys_chunk =
// logical ^ (row&7). ds_read b128: 64 lanes spread 8 lanes per 4-bank group
// = the b128 minimum -> conflict-free. row&7 == ln&7 for all frags (fm*16
// steps) -> per-thread-constant offsets. Both-sides involution: linear
// gload_lds dest + pre-swizzled global source column.
// XCD swizzle (T1, bijective, grid 256 = 16x16).

#define SLOT_U16 16384   // one slot of A (or B): 256 rows * 64 u16 = 32 KB

#define BAR() __builtin_amdgcn_s_barrier()

__global__ __launch_bounds__(512, 2) void gemm256_kernel(const u16* __restrict__ A,
                                                         const u16* __restrict__ B,
                                                         float* __restrict__ C,
                                                         int M, int N, int K) {
    __shared__ u16 As[2 * SLOT_U16];  // 64 KB
    __shared__ u16 Bs[2 * SLOT_U16];  // 64 KB

    const int t   = threadIdx.x;
    const int ln  = t & 63;
    const int wid = t >> 6;          // 0..7
    const int wr  = wid >> 2;        // 0..1 -> M offset wr*128
    const int wc  = wid & 3;         // 0..3 -> N offset wc*64

    // ---- XCD-aware bijective block swizzle (grid 256 = 16 x 16) ----
    const int bid = blockIdx.x;
    const int xcd = bid & 7;
    const int r8  = bid >> 3;            // 0..31
    const int bx  = (xcd & 1) * 8 + (r8 & 7);
    const int by  = (xcd >> 1) * 4 + (r8 >> 3);
    const int m0  = by * 256;
    const int n0  = bx * 256;
    const int NT  = K >> 6;          // 16 K-tiles

    // ---- fragment addressing: row = base + fm*16 + (ln&15); row&7 = ln&7 ----
    const int frow  = ln & 15;
    const int koff0 = (((ln >> 4)    ) ^ (ln & 7)) * 8;   // kk=0 chunk (u16)
    const int koff1 = (((ln >> 4) + 4) ^ (ln & 7)) * 8;   // kk=1 chunk
    const int arow0 = (wr * 128 + frow) * 64;             // + fm*1024
    const int brow0 = (wc * 64  + frow) * 64;             // + fn*1024

    // ---- staging: one load = 64 rows x 8 chunks; thread t -> row t>>3,
    //      phys chunk t&7 -> logical chunk (t&7)^((t>>3)&7).
    const int srow = t >> 3;
    const int scol = ((t & 7) ^ (srow & 7)) * 8;
    const u16* Asrc = A + (size_t)(m0 + srow) * K + scol;
    const u16* Bsrc = B + (size_t)(n0 + srow) * K + scol;

    f32x4 acc[8][4] = {};

    // STG(SRC, DST, H, L, KC): stage rows H*128+L*64.. of tile col KC
#define STG(SRC, DST, H, L, KC)                                              \
    gload_lds16(SRC + (size_t)((H) * 128 + (L) * 64) * K + (KC),             \
                DST + (H) * 8192 + (L) * 4096 + t * 8);

#define READ_A(PH)                                                           \
    a0k0 = *(const bf16x8*)(Ab + arow0 + (2 * (PH)) * 1024 + koff0);         \
    a0k1 = *(const bf16x8*)(Ab + arow0 + (2 * (PH)) * 1024 + koff1);         \
    a1k0 = *(const bf16x8*)(Ab + arow0 + (2 * (PH) + 1) * 1024 + koff0);     \
    a1k1 = *(const bf16x8*)(Ab + arow0 + (2 * (PH) + 1) * 1024 + koff1);

#define MFMA_PH(PH)                                                          \
    _Pragma("unroll")                                                        \
    for (int n = 0; n < 4; ++n) {                                            \
        acc[2*(PH)][n]   = MFMA16(a0k0, bf[n][0], acc[2*(PH)][n],   0,0,0);  \
        acc[2*(PH)][n]   = MFMA16(a0k1, bf[n][1], acc[2*(PH)][n],   0,0,0);  \
        acc[2*(PH)+1][n] = MFMA16(a1k0, bf[n][0], acc[2*(PH)+1][n], 0,0,0);  \
        acc[2*(PH)+1][n] = MFMA16(a1k1, bf[n][1], acc[2*(PH)+1][n], 0,0,0);  \
    }

    // ---- prologue: stage tile 0 fully; drain; rendezvous ----
    STG(Bsrc, Bs, 0, 0, 0) STG(Bsrc, Bs, 0, 1, 0)
    STG(Bsrc, Bs, 1, 0, 0) STG(Bsrc, Bs, 1, 1, 0)
    STG(Asrc, As, 0, 0, 0) STG(Asrc, As, 1, 0, 0)
    STG(Asrc, As, 0, 1, 0) STG(Asrc, As, 1, 1, 0)
    asm volatile("s_waitcnt vmcnt(0)" ::: "memory");
    BAR();

    for (int kt = 0; kt < NT; ++kt) {
        const u16* Ab = As + (kt & 1) * SLOT_U16;
        const u16* Bb = Bs + (kt & 1) * SLOT_U16;
        u16* An = As + ((kt + 1) & 1) * SLOT_U16;
        u16* Bn = Bs + ((kt + 1) & 1) * SLOT_U16;
        const bool pf = (kt + 1) < NT;
        const int kc = (kt + 1) * 64;

        bf16x8 bf[4][2];
        bf16x8 a0k0, a0k1, a1k0, a1k1;

        // ======== phase 0: all B frags + A fm0,1 ; stage B-h0 ========
#pragma unroll
        for (int n = 0; n < 4; ++n) {
            bf[n][0] = *(const bf16x8*)(Bb + brow0 + n * 1024 + koff0);
            bf[n][1] = *(const bf16x8*)(Bb + brow0 + n * 1024 + koff1);
        }
        READ_A(0)
        if (pf) { STG(Bsrc, Bn, 0, 0, kc) STG(Bsrc, Bn, 0, 1, kc) }
        BAR();
        __builtin_amdgcn_s_setprio(1);
        MFMA_PH(0)
        __builtin_amdgcn_s_setprio(0);
        BAR();

        // ======== phase 1: A fm2,3 ; stage B-h1 ; wait own A-L1 ========
        READ_A(1)
        if (pf) { STG(Bsrc, Bn, 1, 0, kc) STG(Bsrc, Bn, 1, 1, kc) }
        BAR();
        __builtin_amdgcn_s_setprio(1);
        MFMA_PH(1)
        __builtin_amdgcn_s_setprio(0);
        if (pf) { asm volatile("s_waitcnt vmcnt(4)" ::: "memory"); }
        else    { asm volatile("s_waitcnt vmcnt(0)" ::: "memory"); }
        BAR();

        // ======== phase 2: A fm4,5 ; stage A L0 pair ========
        READ_A(2)
        if (pf) { STG(Asrc, An, 0, 0, kc) STG(Asrc, An, 1, 0, kc) }
        BAR();
        __builtin_amdgcn_s_setprio(1);
        MFMA_PH(2)
        __builtin_amdgcn_s_setprio(0);
        BAR();

        // ======== phase 3: A fm6,7 ; stage A L1 pair ; boundary vmcnt(2) ========
        READ_A(3)
        if (pf) { STG(Asrc, An, 0, 1, kc) STG(Asrc, An, 1, 1, kc) }
        BAR();
        __builtin_amdgcn_s_setprio(1);
        MFMA_PH(3)
        __builtin_amdgcn_s_setprio(0);
        if (pf) { asm volatile("s_waitcnt vmcnt(2)" ::: "memory"); }
        BAR();
    }
#undef MFMA_PH
#undef READ_A
#undef STG

    // ---- epilogue: C/D layout col=lane&15, row=(lane>>4)*4+reg ----
    const int cr = (ln >> 4) * 4;
    const int cc = ln & 15;
#pragma unroll
    for (int fm = 0; fm < 8; ++fm) {
#pragma unroll
        for (int rr = 0; rr < 4; ++rr) {
            int row = m0 + wr * 128 + fm * 16 + cr + rr;
            float* p = C + (size_t)row * N + n0 + wc * 64 + cc;
#pragma unroll
            for (int fn = 0; fn < 4; ++fn)
                p[fn * 16] = acc[fm][fn][rr];
        }
    }
}

// ---------------- launch ----------------

extern "C" void kernel_launch(void* const* d_in, const int* in_sizes, int n_in,
                              void* d_out, int out_size, void* d_ws, size_t ws_size,
                              hipStream_t stream) {
    const float* x  = (const float*)d_in[0];
    const float* c0 = (const float*)d_in[1];
    const float* c1 = (const float*)d_in[2];
    const float* c2 = (const float*)d_in[3];
    float* out = (float*)d_out;

    const int K = 1024;             // input dim
    const int N = 4096;             // OUT_DIM * SUP
    const int M = in_sizes[0] / K;  // tokens = B*S

    u16* xb = (u16*)d_ws;                        // M*K bf16
    u16* Wt = (u16*)d_ws + (size_t)M * K;        // N*K bf16

    const int convBlocks = (M * K) / (256 * 8);
    pre_kernel<<<convBlocks + 512, 256, 0, stream>>>(x, c0, c1, c2, xb, Wt,
                                                     convBlocks, M * K);

    gemm256_kernel<<<(N / 256) * (M / 256), 512, 0, stream>>>(xb, Wt, out, M, N, K);
}